// Round 15
// baseline (60.210 us; speedup 1.0000x reference)
//
#include <hip/hip_runtime.h>

#define TWO_LOG2E 2.8853901817779268f   // 2*log2(e)
#define LOG2E     1.4426950408889634f

typedef float f32x2 __attribute__((ext_vector_type(2)));
typedef float f32x4 __attribute__((ext_vector_type(4)));

// quad_perm DPP cross-lane (VALU pipe); 0xB1 = lane^1 within quad
template<int CTRL>
__device__ __forceinline__ float dpp_qperm(float x) {
    int r = __builtin_amdgcn_update_dpp(0, __float_as_int(x), CTRL, 0xF, 0xF, true);
    return __int_as_float(r);
}

__device__ __forceinline__ f32x2 splat2(float s) { f32x2 v; v.x = s; v.y = s; return v; }

// full class-MLP -> e^{tanh(o)} given the 4 input features (R12 math)
__device__ __forceinline__ float class_eo(const float* w1c, const f32x2* bwc, float o0,
                                          float mx, float my, float rx, float ry) {
    float o = o0;                              // scaled domain (x 2log2e)
    #pragma unroll
    for (int p = 0; p < 4; ++p) {              // j-pair p: packed layer-1
        const f32x2* wp = (const f32x2*)(w1c + p * 8);
        f32x2 h = bwc[p * 2];                  // bb01
        h = __builtin_elementwise_fma(splat2(mx), wp[0], h);
        h = __builtin_elementwise_fma(splat2(my), wp[1], h);
        h = __builtin_elementwise_fma(splat2(rx), wp[2], h);
        h = __builtin_elementwise_fma(splat2(ry), wp[3], h);
        const float a0 = __builtin_amdgcn_exp2f(h.x) + 1.0f;   // 1+e^{2x}
        const float a1 = __builtin_amdgcn_exp2f(h.y) + 1.0f;
        const float inv = __builtin_amdgcn_rcpf(a0 * a1);
        const f32x2 w2n01 = bwc[p * 2 + 1];
        o = fmaf(w2n01.x, inv * a1, o);        // tanh0 * w2_0 (folded)
        o = fmaf(w2n01.y, inv * a0, o);        // tanh1 * w2_1
    }
    const float e2 = __builtin_amdgcn_exp2f(o);
    const float r2 = __builtin_amdgcn_rcpf(e2 + 1.0f);
    return __builtin_amdgcn_exp2f(fmaf(-TWO_LOG2E, r2, LOG2E)); // e^{tanh}
}

// THREAD = (edge, half): lane h owns classes {2h, 2h+1}. Vs R12's quad layout
// this HALVES the TA address count per edge (10 vs 20 lane-addresses: 16B f32x4
// gathers instead of per-class 8B, f32x2 stores, 2x-redundant idx instead of
// 4x). Theory: the ~26us structure-invariant stall is TA/L1 address-processing
// throughput on the divergent gathers (pipelining/stagger/ILP all null).
__global__ void edge_mlp(
    const float* __restrict__ m,     // [N_NODES, 4, 2]
    const int*   __restrict__ eidx,  // [2, E]
    const float* __restrict__ W1,    // [4, 4, 8]
    const float* __restrict__ b1,    // [4, 8]
    const float* __restrict__ W2,    // [4, 8, 1]
    const float* __restrict__ b2,    // [4, 1]
    float*       __restrict__ out,   // [E, 4]
    const int nE)
{
    __shared__ __align__(16) float sw1[4 * 36]; // [c][p][i][01]=W1[c][i][2p+?]*2log2e
    __shared__ __align__(16) float sbw[4 * 18]; // [c][p]={b1 pair, -2*2log2e*W2 pair}
    __shared__ float so0[4];                    // 2log2e*(b2[c] + sum_j W2[c][j])

    const int tidb = threadIdx.x;
    if (tidb < 128) {
        const int c = tidb >> 5, r = tidb & 31, i = r >> 3, j = r & 7;
        sw1[c * 36 + (j >> 1) * 8 + i * 2 + (j & 1)] =
            W1[c * 32 + i * 8 + j] * TWO_LOG2E;
    } else if (tidb < 192) {
        const int q = tidb - 128, c = q >> 4, r = q & 15, p = r >> 2, k = r & 3;
        const int j = 2 * p + (k & 1);
        sbw[c * 18 + p * 4 + k] =
            (k < 2) ? b1[c * 8 + j] * TWO_LOG2E
                    : W2[c * 8 + j] * (-2.0f * TWO_LOG2E);
    } else if (tidb < 196) {
        const int c = tidb - 192;
        float s = b2[c];
        #pragma unroll
        for (int j = 0; j < 8; ++j) s += W2[c * 8 + j];
        so0[c] = s * TWO_LOG2E;
    }
    __syncthreads();

    const int tid0 = blockIdx.x * blockDim.x + threadIdx.x;
    const int h = tid0 & 1;                     // half: classes 2h, 2h+1
    const int ca = 2 * h;
    const float* wA = sw1 + ca * 36;
    const float* wB = sw1 + (ca + 1) * 36;
    const f32x2* bA = (const f32x2*)(sbw + ca * 18);
    const f32x2* bB = (const f32x2*)(sbw + (ca + 1) * 18);
    const float o0A = so0[ca], o0B = so0[ca + 1];
    const unsigned h4 = (unsigned)(h * 4);

    const int* eidx1 = eidx + nE;
    const int total  = nE * 2;                  // items = (edge, half)
    const int stride = gridDim.x * blockDim.x;  // multiple of 2 -> h constant

    constexpr int UN = 2;
    int t = tid0;

    for (; t + (UN - 1) * stride < total; t += UN * stride) {
        int ri[UN], ci[UN];
        #pragma unroll
        for (int k = 0; k < UN; ++k) {
            const int e = (t + k * stride) >> 1;
            ri[k] = __builtin_nontemporal_load(eidx  + e);
            ci[k] = __builtin_nontemporal_load(eidx1 + e);
        }
        f32x4 fc[UN], fr[UN];                   // this half's 16B of col/row rows
        #pragma unroll
        for (int k = 0; k < UN; ++k) {
            fc[k] = *(const f32x4*)(m + (unsigned)ci[k] * 8u + h4);
            fr[k] = *(const f32x4*)(m + (unsigned)ri[k] * 8u + h4);
        }
        #pragma unroll
        for (int k = 0; k < UN; ++k) {
            const float eoA = class_eo(wA, bA, o0A, fc[k].x, fc[k].y, fr[k].x, fr[k].y);
            const float eoB = class_eo(wB, bB, o0B, fc[k].z, fc[k].w, fr[k].z, fr[k].w);
            const float sp = eoA + eoB;
            const float s  = sp + dpp_qperm<0xB1>(sp);   // + other half's pair
            const float rs = __builtin_amdgcn_rcpf(s);
            f32x2 res; res.x = eoA * rs; res.y = eoB * rs;
            const int e = (t + k * stride) >> 1;
            __builtin_nontemporal_store(res,
                (f32x2*)(out + ((unsigned)e << 2) + 2u * h));
        }
    }

    // tail
    for (; t < total; t += stride) {
        const int e = t >> 1;
        const int r0 = eidx[e];
        const int c0 = eidx1[e];
        const f32x4 fc0 = *(const f32x4*)(m + (unsigned)c0 * 8u + h4);
        const f32x4 fr0 = *(const f32x4*)(m + (unsigned)r0 * 8u + h4);
        const float eoA = class_eo(wA, bA, o0A, fc0.x, fc0.y, fr0.x, fr0.y);
        const float eoB = class_eo(wB, bB, o0B, fc0.z, fc0.w, fr0.z, fr0.w);
        const float sp = eoA + eoB;
        const float s  = sp + dpp_qperm<0xB1>(sp);
        const float rs = __builtin_amdgcn_rcpf(s);
        f32x2 res; res.x = eoA * rs; res.y = eoB * rs;
        __builtin_nontemporal_store(res, (f32x2*)(out + ((unsigned)e << 2) + 2u * h));
    }
}

extern "C" void kernel_launch(void* const* d_in, const int* in_sizes, int n_in,
                              void* d_out, int out_size, void* d_ws, size_t ws_size,
                              hipStream_t stream) {
    const float* m  = (const float*)d_in[0];
    const int* eidx = (const int*)d_in[1];
    const float* W1 = (const float*)d_in[2];
    const float* b1 = (const float*)d_in[3];
    const float* W2 = (const float*)d_in[4];
    const float* b2 = (const float*)d_in[5];
    float* out = (float*)d_out;
    const int nE = in_sizes[1] / 2;

    const int threads = 256;
    const int blocks  = 2048;
    hipLaunchKernelGGL(edge_mlp, dim3(blocks), dim3(threads), 0, stream,
                       m, eidx, W1, b1, W2, b2, out, nE);
}